// Round 5
// baseline (153.312 us; speedup 1.0000x reference)
//
#include <hip/hip_runtime.h>

static constexpr int NS    = 1024;   // N
static constexpr int KR    = 17;     // K
static constexpr int NROWS = NS * KR;

__device__ inline float wave_sum(float v) {
#pragma unroll
    for (int s = 32; s > 0; s >>= 1) v += __shfl_xor(v, s, 64);
    return v;
}
// reductions within an aligned 16-lane group (xor distances stay in-group)
__device__ inline float grp_sum16(float v) {
#pragma unroll
    for (int s = 8; s > 0; s >>= 1) v += __shfl_xor(v, s, 64);
    return v;
}
__device__ inline float grp_max16(float v) {
#pragma unroll
    for (int s = 8; s > 0; s >>= 1) v = fmaxf(v, __shfl_xor(v, s, 64));
    return v;
}

// 16 lanes per row; lane `sub` of the group reads float4 stripes.
//   lesser = all(pred < 3) == max(pred) < 3
//   BCE rows: mean( max(p,0) - p*g ) + mean( log(1+e^-|p|) )  [log of product]
//   KLD rows: (T1 - T2)/S - log(S) + lse, e = exp(10g) unshifted (fp32-safe)
template <int W>
__device__ __forceinline__ void row_body16(
    const float* __restrict__ pred, const float* __restrict__ gt,
    float* __restrict__ loss, int* __restrict__ flag, int row, int sub) {
    constexpr int EP = W / 64;  // float4 per lane: 6 for 384, 8 for 512
    const float4* p4 = (const float4*)(pred + (size_t)row * W);
    const float4* g4 = (const float4*)(gt   + (size_t)row * W);

    // issue ALL loads up front — 4 rows per wave in flight
    float4 pv[EP], gv[EP];
#pragma unroll
    for (int j = 0; j < EP; ++j) {
        pv[j] = p4[sub + 16 * j];
        gv[j] = g4[sub + 16 * j];
    }

    float mp = -1e30f;
#pragma unroll
    for (int j = 0; j < EP; ++j)
        mp = fmaxf(mp, fmaxf(fmaxf(pv[j].x, pv[j].y), fmaxf(pv[j].z, pv[j].w)));
    mp = grp_max16(mp);
    const float inv = 1.0f / (float)W;

    if (mp < 3.0f) {  // BCE (per-group; divergence acceptable, latency-bound)
        float lin = 0.f, prod = 1.f;
#pragma unroll
        for (int j = 0; j < EP; ++j) {
            float pe[4] = {pv[j].x, pv[j].y, pv[j].z, pv[j].w};
            float ge[4] = {gv[j].x, gv[j].y, gv[j].z, gv[j].w};
#pragma unroll
            for (int t = 0; t < 4; ++t) {
                float p = pe[t];
                lin  += fmaxf(p, 0.f) - p * ge[t];
                prod *= 1.f + __expf(-fabsf(p));  // prod <= 2^32, safe
            }
        }
        float v = grp_sum16(lin + __logf(prod));
        if (sub == 0) { loss[row] = v * inv; flag[row] = 1; }
    } else {          // KLD
        float sp = 0.f, S = 0.f, T1 = 0.f, T2 = 0.f;
#pragma unroll
        for (int j = 0; j < EP; ++j) {
            float pe[4] = {pv[j].x, pv[j].y, pv[j].z, pv[j].w};
            float ge[4] = {gv[j].x, gv[j].y, gv[j].z, gv[j].w};
#pragma unroll
            for (int t = 0; t < 4; ++t) {
                float p   = pe[t];
                float g10 = 10.0f * ge[t];
                sp += __expf(p - mp);
                float e = __expf(g10);
                S  += e;
                T1 += e * g10;
                T2 += e * p;
            }
        }
        sp = grp_sum16(sp);
        S  = grp_sum16(S);
        T1 = grp_sum16(T1);
        T2 = grp_sum16(T2);
        if (sub == 0) {
            loss[row] = ((T1 - T2) / S - __logf(S) + mp + __logf(sp)) * inv;
            flag[row] = 0;
        }
    }
}

static constexpr int BLOCKS_PER_AXIS = NROWS / 16;  // 1088 (16 rows per block)

__global__ __launch_bounds__(256) void row_loss_all(
    const float* __restrict__ px, const float* __restrict__ gx,
    const float* __restrict__ py, const float* __restrict__ gy,
    float* __restrict__ lx, int* __restrict__ fx,
    float* __restrict__ ly, int* __restrict__ fy) {
    const int widx = threadIdx.x >> 6;
    const int lane = threadIdx.x & 63;
    const int grp  = lane >> 4;
    const int sub  = lane & 15;
    const int b    = (int)blockIdx.x;
    if (b < BLOCKS_PER_AXIS) {
        int row = (b * 4 + widx) * 4 + grp;
        row_body16<384>(px, gx, lx, fx, row, sub);
    } else {
        int row = ((b - BLOCKS_PER_AXIS) * 4 + widx) * 4 + grp;
        row_body16<512>(py, gy, ly, fy, row, sub);
    }
}

// One wave per sample. Stable-argsort permutation in closed form via ballot:
// KLD rows (f==0) keep original order first, then BCE rows (f==1).
__global__ __launch_bounds__(256) void combine_kernel(
    const float* __restrict__ lx, const int* __restrict__ fx,
    const float* __restrict__ ly, const int* __restrict__ fy,
    const float* __restrict__ w, float* __restrict__ partial) {
    const int widx = threadIdx.x >> 6;
    const int lane = threadIdx.x & 63;
    const int n = blockIdx.x * 4 + widx;  // grid = NS/4 blocks
    const float* wn = w + n * KR;
    const unsigned long long below = (1ULL << lane) - 1ULL;

    float acc = 0.f;
    {
        int f = 1; float l = 0.f;
        if (lane < KR) { f = fx[n * KR + lane]; l = lx[n * KR + lane]; }
        unsigned long long mk = __ballot(lane < KR && !f);  // KLD rows
        int nk = __popcll(mk);
        int pos = f ? nk + __popcll(~mk & below) : __popcll(mk & below);
        if (lane < KR) acc += l * wn[pos];
    }
    {
        int f = 1; float l = 0.f;
        if (lane < KR) { f = fy[n * KR + lane]; l = ly[n * KR + lane]; }
        unsigned long long mk = __ballot(lane < KR && !f);
        int nk = __popcll(mk);
        int pos = f ? nk + __popcll(~mk & below) : __popcll(mk & below);
        if (lane < KR) acc += l * wn[pos];
    }
    acc = wave_sum(acc);
    __shared__ float s[4];
    if (lane == 0) s[widx] = acc;
    __syncthreads();
    if (threadIdx.x == 0)
        partial[blockIdx.x] = s[0] + s[1] + s[2] + s[3];
}

// Deterministic final reduction of NS/4 = 256 partials, /K.
__global__ __launch_bounds__(256) void final_reduce_kernel(
    const float* __restrict__ partial, float* __restrict__ out) {
    float v = partial[threadIdx.x];  // exactly 256 partials
    v = wave_sum(v);
    __shared__ float s[4];
    if ((threadIdx.x & 63) == 0) s[threadIdx.x >> 6] = v;
    __syncthreads();
    if (threadIdx.x == 0)
        out[0] = (s[0] + s[1] + s[2] + s[3]) * (1.0f / (float)KR);
}

extern "C" void kernel_launch(void* const* d_in, const int* in_sizes, int n_in,
                              void* d_out, int out_size, void* d_ws, size_t ws_size,
                              hipStream_t stream) {
    const float* pred_x = (const float*)d_in[0];
    const float* pred_y = (const float*)d_in[1];
    const float* gt_x   = (const float*)d_in[2];
    const float* gt_y   = (const float*)d_in[3];
    const float* tw     = (const float*)d_in[4];

    // workspace: lx | ly | fx | fy | partial  (all 4 B elems)
    float* lx      = (float*)d_ws;
    float* ly      = lx + NROWS;
    int*   fx      = (int*)(ly + NROWS);
    int*   fy      = fx + NROWS;
    float* partial = (float*)(fy + NROWS);

    row_loss_all<<<2 * BLOCKS_PER_AXIS, 256, 0, stream>>>(
        pred_x, gt_x, pred_y, gt_y, lx, fx, ly, fy);
    combine_kernel<<<NS / 4, 256, 0, stream>>>(lx, fx, ly, fy, tw, partial);
    final_reduce_kernel<<<1, 256, 0, stream>>>(partial, (float*)d_out);
}

// Round 6
// 152.544 us; speedup vs baseline: 1.0050x; 1.0050x over previous
//
#include <hip/hip_runtime.h>

static constexpr int NS    = 1024;   // N
static constexpr int KR    = 17;     // K
static constexpr int NROWS = NS * KR;

__device__ inline float wave_sum(float v) {
#pragma unroll
    for (int s = 32; s > 0; s >>= 1) v += __shfl_xor(v, s, 64);
    return v;
}
// reductions within an aligned 16-lane group (xor distances stay in-group)
__device__ inline float grp_sum16(float v) {
#pragma unroll
    for (int s = 8; s > 0; s >>= 1) v += __shfl_xor(v, s, 64);
    return v;
}
__device__ inline float grp_max16(float v) {
#pragma unroll
    for (int s = 8; s > 0; s >>= 1) v = fmaxf(v, __shfl_xor(v, s, 64));
    return v;
}

// 16 lanes per row; lane `sub` of the group reads float4 stripes.
//   lesser = all(pred < 3) == max(pred) < 3
//   BCE rows: mean( max(p,0) - p*g ) + mean( log(1+e^-|p|) )  [log of product]
//   KLD rows: (T1 - T2)/S - log(S) + lse, e = exp(10g) unshifted (fp32-safe)
template <int W>
__device__ __forceinline__ void row_body16(
    const float* __restrict__ pred, const float* __restrict__ gt,
    float* __restrict__ loss, int* __restrict__ flag, int row, int sub) {
    constexpr int EP = W / 64;  // float4 per lane: 6 for 384, 8 for 512
    const float4* p4 = (const float4*)(pred + (size_t)row * W);
    const float4* g4 = (const float4*)(gt   + (size_t)row * W);

    // issue ALL loads up front — 4 rows per wave in flight
    float4 pv[EP], gv[EP];
#pragma unroll
    for (int j = 0; j < EP; ++j) {
        pv[j] = p4[sub + 16 * j];
        gv[j] = g4[sub + 16 * j];
    }

    float mp = -1e30f;
#pragma unroll
    for (int j = 0; j < EP; ++j)
        mp = fmaxf(mp, fmaxf(fmaxf(pv[j].x, pv[j].y), fmaxf(pv[j].z, pv[j].w)));
    mp = grp_max16(mp);
    const float inv = 1.0f / (float)W;

    if (mp < 3.0f) {  // BCE (per-group divergence acceptable, nothing saturated)
        float lin = 0.f, prod = 1.f;
#pragma unroll
        for (int j = 0; j < EP; ++j) {
            float pe[4] = {pv[j].x, pv[j].y, pv[j].z, pv[j].w};
            float ge[4] = {gv[j].x, gv[j].y, gv[j].z, gv[j].w};
#pragma unroll
            for (int t = 0; t < 4; ++t) {
                float p = pe[t];
                lin  += fmaxf(p, 0.f) - p * ge[t];
                prod *= 1.f + __expf(-fabsf(p));  // prod <= 2^32, safe
            }
        }
        float v = grp_sum16(lin + __logf(prod));
        if (sub == 0) { loss[row] = v * inv; flag[row] = 1; }
    } else {          // KLD
        float sp = 0.f, S = 0.f, T1 = 0.f, T2 = 0.f;
#pragma unroll
        for (int j = 0; j < EP; ++j) {
            float pe[4] = {pv[j].x, pv[j].y, pv[j].z, pv[j].w};
            float ge[4] = {gv[j].x, gv[j].y, gv[j].z, gv[j].w};
#pragma unroll
            for (int t = 0; t < 4; ++t) {
                float p   = pe[t];
                float g10 = 10.0f * ge[t];
                sp += __expf(p - mp);
                float e = __expf(g10);
                S  += e;
                T1 += e * g10;
                T2 += e * p;
            }
        }
        sp = grp_sum16(sp);
        S  = grp_sum16(S);
        T1 = grp_sum16(T1);
        T2 = grp_sum16(T2);
        if (sub == 0) {
            loss[row] = ((T1 - T2) / S - __logf(S) + mp + __logf(sp)) * inv;
            flag[row] = 0;
        }
    }
}

static constexpr int BPA   = NROWS / 16;  // 1088 units per axis (16 rows/unit)
static constexpr int UNITS = 2 * BPA;     // 2176
static constexpr int GRID  = 2048;        // exactly 8 blocks/CU co-resident

__global__ __launch_bounds__(256) void row_loss_all(
    const float* __restrict__ px, const float* __restrict__ gx,
    const float* __restrict__ py, const float* __restrict__ gy,
    float* __restrict__ lx, int* __restrict__ fx,
    float* __restrict__ ly, int* __restrict__ fy) {
    const int widx = threadIdx.x >> 6;
    const int lane = threadIdx.x & 63;
    const int grp  = lane >> 4;
    const int sub  = lane & 15;
    for (int u = (int)blockIdx.x; u < UNITS; u += GRID) {
        if (u < BPA) {
            int row = (u * 4 + widx) * 4 + grp;
            row_body16<384>(px, gx, lx, fx, row, sub);
        } else {
            int row = ((u - BPA) * 4 + widx) * 4 + grp;
            row_body16<512>(py, gy, ly, fy, row, sub);
        }
    }
}

// One wave per sample. Stable-argsort permutation in closed form via ballot:
// KLD rows (f==0) keep original order first, then BCE rows (f==1).
// Each block adds its partial (scaled by 1/K) straight into out[0].
__global__ __launch_bounds__(256) void combine_atomic_kernel(
    const float* __restrict__ lx, const int* __restrict__ fx,
    const float* __restrict__ ly, const int* __restrict__ fy,
    const float* __restrict__ w, float* __restrict__ out) {
    const int widx = threadIdx.x >> 6;
    const int lane = threadIdx.x & 63;
    const int n = blockIdx.x * 4 + widx;  // grid = NS/4 blocks
    const float* wn = w + n * KR;
    const unsigned long long below = (1ULL << lane) - 1ULL;

    float acc = 0.f;
    {
        int f = 1; float l = 0.f;
        if (lane < KR) { f = fx[n * KR + lane]; l = lx[n * KR + lane]; }
        unsigned long long mk = __ballot(lane < KR && !f);  // KLD rows
        int nk = __popcll(mk);
        int pos = f ? nk + __popcll(~mk & below) : __popcll(mk & below);
        if (lane < KR) acc += l * wn[pos];
    }
    {
        int f = 1; float l = 0.f;
        if (lane < KR) { f = fy[n * KR + lane]; l = ly[n * KR + lane]; }
        unsigned long long mk = __ballot(lane < KR && !f);
        int nk = __popcll(mk);
        int pos = f ? nk + __popcll(~mk & below) : __popcll(mk & below);
        if (lane < KR) acc += l * wn[pos];
    }
    acc = wave_sum(acc);
    __shared__ float s[4];
    if (lane == 0) s[widx] = acc;
    __syncthreads();
    if (threadIdx.x == 0)
        atomicAdd(out, (s[0] + s[1] + s[2] + s[3]) * (1.0f / (float)KR));
}

extern "C" void kernel_launch(void* const* d_in, const int* in_sizes, int n_in,
                              void* d_out, int out_size, void* d_ws, size_t ws_size,
                              hipStream_t stream) {
    const float* pred_x = (const float*)d_in[0];
    const float* pred_y = (const float*)d_in[1];
    const float* gt_x   = (const float*)d_in[2];
    const float* gt_y   = (const float*)d_in[3];
    const float* tw     = (const float*)d_in[4];

    // workspace: lx | ly | fx | fy  (all 4 B elems)
    float* lx = (float*)d_ws;
    float* ly = lx + NROWS;
    int*   fx = (int*)(ly + NROWS);
    int*   fy = fx + NROWS;

    // d_out is poisoned to 0xAA before every timed launch — zero it in-graph.
    hipMemsetAsync(d_out, 0, sizeof(float), stream);

    row_loss_all<<<GRID, 256, 0, stream>>>(pred_x, gt_x, pred_y, gt_y,
                                           lx, fx, ly, fy);
    combine_atomic_kernel<<<NS / 4, 256, 0, stream>>>(lx, fx, ly, fy, tw,
                                                      (float*)d_out);
}